// Round 7
// baseline (283.695 us; speedup 1.0000x reference)
//
#include <hip/hip_runtime.h>

// Problem constants (fixed by setup_inputs: B=64, C=16, T=32768, fp32)
#define B_BATCH 64
#define C_CH    16
#define T_LEN   32768
#define THREADS 512                  // 8 waves/block
#define NWAVE   (THREADS / 64)
#define CHUNK   2048                 // elements per chunk (8 KB per array)
#define NCHUNK  (T_LEN / CHUNK)      // 16 chunks per row
#define NROWS   (B_BATCH * C_CH)     // 1024 rows -> 1024 blocks, 4/CU

// T3 2-phase pipeline (m230/m248 recipe), memory-bound variant:
//  - stage next chunk to LDS via global_load_lds (no VGPR dest, no round-trip)
//  - RAW s_barrier with counted s_waitcnt vmcnt(2): the next chunk's 2 stage
//    loads stay IN FLIGHT across the barrier. __syncthreads would emit
//    vmcnt(0) and drain them every chunk (the R0/R6 stall).
//  - totals-exchange barrier waits lgkmcnt(0) only (no vmem drain).
__device__ __forceinline__ void stage16(const float* g, float* l) {
    __builtin_amdgcn_global_load_lds(
        (const __attribute__((address_space(1))) unsigned int*)g,
        (__attribute__((address_space(3))) unsigned int*)l, 16, 0, 0);
}

__global__ __launch_bounds__(THREADS, 8) void wloss_scan_kernel(
    const float* __restrict__ pred,
    const float* __restrict__ tru,
    double* __restrict__ partials)
{
    __shared__ float  sP[2][CHUNK];     // 2 x 8 KB staged pred
    __shared__ float  sT[2][CHUNK];     // 2 x 8 KB staged tru
    __shared__ float  s_wt[2][NWAVE];   // parity wave totals
    __shared__ double s_d[NWAVE];

    const int row  = blockIdx.x;
    const int tid  = threadIdx.x;
    const int lane = tid & 63;
    const int wave = tid >> 6;

    const float* Pr = pred + (size_t)row * T_LEN;
    const float* Tr = tru  + (size_t)row * T_LEN;

    // Stage chunk ch into buffer b: each thread stages 16 B of each array.
    // LDS dest must be wave-uniform base (HW adds lane*16); global src per-lane.
    // wave w covers floats [ch*CHUNK + w*256, +256) -> LDS floats [w*256, +256).
#define STAGE(ch, b) do {                                   \
        const int _o = (ch) * CHUNK + (tid << 2);           \
        stage16(Pr + _o, &sP[b][wave << 8]);                \
        stage16(Tr + _o, &sT[b][wave << 8]);                \
    } while (0)

    float  carry = 0.0f;
    double acc   = 0.0;

    STAGE(0, 0);                        // prologue: chunk 0 in flight

    for (int ch = 0; ch < NCHUNK; ++ch) {
        const int buf = ch & 1;
        if (ch + 1 < NCHUNK) {
            STAGE(ch + 1, buf ^ 1);     // issue next chunk's 2 stage-loads
            // wait for chunk ch's 2 loads only; leave ch+1's 2 outstanding
            asm volatile("s_waitcnt vmcnt(2)" ::: "memory");
        } else {
            asm volatile("s_waitcnt vmcnt(0)" ::: "memory");
        }
        __builtin_amdgcn_sched_barrier(0);
        __builtin_amdgcn_s_barrier();   // chunk ch fully staged (all waves)
        __builtin_amdgcn_sched_barrier(0);

        // this thread's 4 elements, contiguous 16 B (conflict-free b128 reads)
        float4 p = *(const float4*)&sP[buf][tid << 2];
        float4 t = *(const float4*)&sT[buf][tid << 2];
        float s1 = p.x - t.x;
        float s2 = s1 + (p.y - t.y);
        float s3 = s2 + (p.z - t.z);
        float s4 = s3 + (p.w - t.w);

        float v = s4;                   // wave-inclusive scan of thread totals
        #pragma unroll
        for (int off = 1; off < 64; off <<= 1) {
            float u = __shfl_up(v, off, 64);
            if (lane >= off) v += u;
        }
        if (lane == 63) s_wt[buf][wave] = v;

        asm volatile("s_waitcnt lgkmcnt(0)" ::: "memory"); // totals write visible
        __builtin_amdgcn_sched_barrier(0);
        __builtin_amdgcn_s_barrier();   // NOTE: no vmcnt drain here
        __builtin_amdgcn_sched_barrier(0);

        float wpre = 0.0f, tot = 0.0f;
        #pragma unroll
        for (int w = 0; w < NWAVE; ++w) {
            float wt = s_wt[buf][w];    // broadcast read
            if (w < wave) wpre += wt;
            tot += wt;
        }

        const float excl = carry + wpre + (v - s4);
        const int   e0   = ch * CHUNK + (tid << 2);
        const float w0   = (float)(T_LEN - e0);
        float part = fabsf(excl + s1) *  w0
                   + fabsf(excl + s2) * (w0 - 1.0f)
                   + fabsf(excl + s3) * (w0 - 2.0f)
                   + fabsf(excl + s4) * (w0 - 3.0f);
        acc   += (double)part;
        carry += tot;
    }
#undef STAGE

    // block reduction of double acc (regular __syncthreads is fine here)
    #pragma unroll
    for (int off = 32; off > 0; off >>= 1)
        acc += __shfl_down(acc, off, 64);
    if (lane == 0) s_d[wave] = acc;
    __syncthreads();

    if (tid == 0) {
        double s = 0.0;
        #pragma unroll
        for (int w = 0; w < NWAVE; ++w) s += s_d[w];
        partials[row] = s;              // plain store, no atomics anywhere
    }
}

__global__ __launch_bounds__(256) void wloss_finalize_kernel(
    const double* __restrict__ partials, float* __restrict__ out)
{
    const int tid  = threadIdx.x;
    const int lane = tid & 63;
    const int wave = tid >> 6;

    double acc = 0.0;
    for (int i = tid; i < NROWS; i += 256) acc += partials[i];

    #pragma unroll
    for (int off = 32; off > 0; off >>= 1)
        acc += __shfl_down(acc, off, 64);

    __shared__ double dtot[4];
    if (lane == 0) dtot[wave] = acc;
    __syncthreads();

    if (tid == 0) {
        const double tot     = dtot[0] + dtot[1] + dtot[2] + dtot[3];
        const double tc      = (double)T_LEN * (double)C_CH;      // 524288
        const double scaling = 2.0 / (tc * (tc + 1.0));
        out[0] = (float)(tot * scaling / (double)B_BATCH);
    }
}

extern "C" void kernel_launch(void* const* d_in, const int* in_sizes, int n_in,
                              void* d_out, int out_size, void* d_ws, size_t ws_size,
                              hipStream_t stream)
{
    const float* pred = (const float*)d_in[0];
    const float* tru  = (const float*)d_in[1];
    double* partials  = (double*)d_ws;     // 1024 doubles, fully overwritten
    float*  out       = (float*)d_out;

    // No memset needed: every partial is written before finalize reads it.
    wloss_scan_kernel    <<<NROWS, THREADS, 0, stream>>>(pred, tru, partials);
    wloss_finalize_kernel<<<1,     256,     0, stream>>>(partials, out);
}

// Round 8
// 278.231 us; speedup vs baseline: 1.0196x; 1.0196x over previous
//
#include <hip/hip_runtime.h>

// Problem constants (fixed by setup_inputs: B=64, C=16, T=32768, fp32)
#define B_BATCH 64
#define C_CH    16
#define T_LEN   32768
#define THREADS 512                   // 8 waves; wave w owns row span [4096w, +4096)
#define NWAVE   8
#define WSPAN   4096                  // elements per wave
#define NSLICE  16                    // 256-elem slices per wave span
#define NROWS   (B_BATCH * C_CH)      // 1024 rows -> 1024 blocks

// One row per 512-thread block, whole row resident in registers.
//  - every load instruction is a coalesced 1 KB (64 lanes x float4)
//  - 4-slice x 2-array prefetch ring: ~8 load-instrs in flight per wave,
//    sustained; 8 waves/CU -> ~64 KB outstanding per CU (max read pressure)
//  - 16 independent wave-scans (no cross-slice serialization); slice-prefix
//    resolved per-thread in registers; ONE barrier per row (vs 32 in R0/R7)
//  - launch_bounds(512,2): VGPR cap 256, enough for ~150 live regs -> the
//    pipeline cannot be sunk (the R5 failure mode) and cannot spill
__global__ __launch_bounds__(THREADS, 2) void wloss_row_kernel(
    const float* __restrict__ pred,
    const float* __restrict__ tru,
    double* __restrict__ partials)
{
    __shared__ float  s_wt[NWAVE];
    __shared__ double s_d[NWAVE];

    const int row  = blockIdx.x;
    const int tid  = threadIdx.x;
    const int lane = tid & 63;
    const int wave = tid >> 6;

    // wave's span; slice g = float4 indices [64g, 64g+64), lane l takes 64g+l
    const float4* P = (const float4*)(pred + (size_t)row * T_LEN + wave * WSPAN) + lane;
    const float4* Q = (const float4*)(tru  + (size_t)row * T_LEN + wave * WSPAN) + lane;

    // per-slice register state (full unroll -> static indexing, stays in VGPRs)
    float a_[NSLICE], b_[NSLICE], c_[NSLICE], d_[NSLICE];  // local prefixes s1..s4
    float e_[NSLICE];                                      // lane-exclusive offset
    float tot_[NSLICE];                                    // slice totals (uniform)

    // prefetch ring: 4 slices x 2 arrays in flight
    float4 pb[4], tb[4];
    #pragma unroll
    for (int i = 0; i < 4; ++i) { pb[i] = P[i * 64]; tb[i] = Q[i * 64]; }

    #pragma unroll
    for (int g = 0; g < NSLICE; ++g) {
        float4 p = pb[g & 3], t = tb[g & 3];
        if (g + 4 < NSLICE) {                 // refill ring (static predicate)
            pb[g & 3] = P[(g + 4) * 64];
            tb[g & 3] = Q[(g + 4) * 64];
        }
        float s1 = p.x - t.x;
        float s2 = s1 + (p.y - t.y);
        float s3 = s2 + (p.z - t.z);
        float s4 = s3 + (p.w - t.w);

        float v = s4;                          // wave-inclusive scan (independent per slice)
        #pragma unroll
        for (int off = 1; off < 64; off <<= 1) {
            float u = __shfl_up(v, off, 64);
            if (lane >= off) v += u;
        }
        a_[g] = s1; b_[g] = s2; c_[g] = s3; d_[g] = s4;
        e_[g] = v - s4;                        // in-wave exclusive prefix
        tot_[g] = __shfl(v, 63, 64);           // slice total, broadcast to all lanes
    }

    // cross-wave exchange: ONE barrier per row
    float wtot = 0.f;
    #pragma unroll
    for (int g = 0; g < NSLICE; ++g) wtot += tot_[g];
    if (lane == 0) s_wt[wave] = wtot;
    __syncthreads();

    float run = 0.f;                           // exclusive prefix of earlier waves
    #pragma unroll
    for (int w = 0; w < NWAVE; ++w) {
        float wt = s_wt[w];
        if (w < wave) run += wt;
    }

    // weighted |cumsum| pass, all from registers; slice-prefix resolved per-thread
    double acc = 0.0;
    #pragma unroll
    for (int g = 0; g < NSLICE; ++g) {
        const float excl = run + e_[g];
        const int   e0   = wave * WSPAN + g * 256 + lane * 4;   // row-local index
        const float w0   = (float)(T_LEN - e0);
        float part = fabsf(excl + a_[g]) *  w0
                   + fabsf(excl + b_[g]) * (w0 - 1.0f)
                   + fabsf(excl + c_[g]) * (w0 - 2.0f)
                   + fabsf(excl + d_[g]) * (w0 - 3.0f);
        acc += (double)part;                   // same 4-term fp32 granularity as R0
        run += tot_[g];
    }

    // block reduction of double acc across 8 waves
    #pragma unroll
    for (int off = 32; off > 0; off >>= 1)
        acc += __shfl_down(acc, off, 64);
    if (lane == 0) s_d[wave] = acc;
    __syncthreads();

    if (tid == 0) {
        double s = 0.0;
        #pragma unroll
        for (int w = 0; w < NWAVE; ++w) s += s_d[w];
        partials[row] = s;                     // plain store, no atomics anywhere
    }
}

__global__ __launch_bounds__(256) void wloss_finalize_kernel(
    const double* __restrict__ partials, float* __restrict__ out)
{
    const int tid  = threadIdx.x;
    const int lane = tid & 63;
    const int wave = tid >> 6;

    double acc = 0.0;
    for (int i = tid; i < NROWS; i += 256) acc += partials[i];

    #pragma unroll
    for (int off = 32; off > 0; off >>= 1)
        acc += __shfl_down(acc, off, 64);

    __shared__ double dtot[4];
    if (lane == 0) dtot[wave] = acc;
    __syncthreads();

    if (tid == 0) {
        const double tot     = dtot[0] + dtot[1] + dtot[2] + dtot[3];
        const double tc      = (double)T_LEN * (double)C_CH;      // 524288
        const double scaling = 2.0 / (tc * (tc + 1.0));
        out[0] = (float)(tot * scaling / (double)B_BATCH);
    }
}

extern "C" void kernel_launch(void* const* d_in, const int* in_sizes, int n_in,
                              void* d_out, int out_size, void* d_ws, size_t ws_size,
                              hipStream_t stream)
{
    const float* pred = (const float*)d_in[0];
    const float* tru  = (const float*)d_in[1];
    double* partials  = (double*)d_ws;     // 1024 doubles, fully overwritten
    float*  out       = (float*)d_out;

    // No memset needed: every partial is written before finalize reads it.
    wloss_row_kernel     <<<NROWS, THREADS, 0, stream>>>(pred, tru, partials);
    wloss_finalize_kernel<<<1,     256,     0, stream>>>(partials, out);
}